// Round 12
// baseline (233.510 us; speedup 1.0000x reference)
//
#include <hip/hip_runtime.h>
#include <hip/hip_bf16.h>

#define NN 10000
#define EE 320000
#define EALL (EE + NN)   // 330000 edges incl. self loops
#define BG 64
#define AOUT 1024

#define WTOT 191361        // packed fp32 weight elements

#define DRANGE 2560        // dst range per CSR block (4 * 2560 = 10240 >= 10000)
#define DNB 4              // R24: 4x fewer edge re-reads in hist+scatter
#define NSEG 64            // edge-stream segments (parallelism for CSR build)
#define ESEG 5157          // ceil(330000 / 64)

typedef __hip_bfloat16 bf16;
typedef __attribute__((ext_vector_type(8))) short bf16x8;   // 8 bf16 (4 VGPRs)
typedef __attribute__((ext_vector_type(4))) float f32x4;

__device__ __forceinline__ unsigned short f2bf(float f) {
    bf16 h = __float2bfloat16(f);
    return *reinterpret_cast<unsigned short*>(&h);
}
__device__ __forceinline__ float bf2f(unsigned short u) {
    bf16 h;
    *reinterpret_cast<unsigned short*>(&h) = u;
    return __bfloat162float(h);
}
// raw edge/batch element read with uniform dtype branch (fi=1: int32, fi=0: int64)
__device__ __forceinline__ int iread(const void* p, int fi, long long idx) {
    return fi ? ((const int*)p)[idx] : (int)((const long long*)p)[idx];
}

// ====== R26: conversion kernel ONLY handles weights (fp32 copy + W1/W2/W3 -> bf16^T). ======
struct WPtrs { const void* p[20]; };
__global__ __launch_bounds__(256) void k_cvt_all(WPtrs wp, const void* __restrict__ xsrc,
                          float* __restrict__ wf,
                          unsigned short* __restrict__ w1t, unsigned short* __restrict__ w2t,
                          unsigned short* __restrict__ w3t, int ffh) {
    __shared__ int sff;
    int ff = ffh;
    if (ffh < 0) {   // sample leading 16K x-halves: any bf16-NaN pattern => fp32 storage
        const int t = threadIdx.x;
        bool nanp = false;
        const uint4* xs4 = (const uint4*)xsrc;
        uint4 a = xs4[t * 8 + 0], b = xs4[t * 8 + 4];
        const unsigned int wds[8] = {a.x, a.y, a.z, a.w, b.x, b.y, b.z, b.w};
#pragma unroll
        for (int k = 0; k < 8; k++) {
            unsigned int w2 = wds[k];
            if ((w2 & 0x7F80u) == 0x7F80u || ((w2 >> 16) & 0x7F80u) == 0x7F80u) nanp = true;
        }
        unsigned long long bn = __ballot(nanp);
        if (t == 0) sff = 0;
        __syncthreads();
        if ((t & 63) == 0 && bn) atomicOr(&sff, 1);
        __syncthreads();
        ff = sff;
    }

    const int sz[20] = {32768,256,256,256,65536,256,256,256,16384,64,64,64,4096,64,65536,1024,4096,64,64,1};
    int i = blockIdx.x * 256 + threadIdx.x;
    if (i < WTOT) {
        int seg = 0, off = 0;
        while (i - off >= sz[seg]) { off += sz[seg]; seg++; }
        const void* src = wp.p[seg];
        int k = i - off;
        wf[i] = ff ? ((const float*)src)[k] : __bfloat162float(((const bf16*)src)[k]);
        return;
    }
    i -= WTOT;
    if (i < 32768) {  // W1 [128x256] -> w1t [256][128] bf16
        int k = i >> 8, c = i & 255;
        float v = ff ? ((const float*)wp.p[0])[i] : __bfloat162float(((const bf16*)wp.p[0])[i]);
        w1t[c * 128 + k] = f2bf(v);
        return;
    }
    i -= 32768;
    if (i < 65536) {  // W2 [256x256] -> w2t [256][256] bf16
        int k = i >> 8, c = i & 255;
        float v = ff ? ((const float*)wp.p[4])[i] : __bfloat162float(((const bf16*)wp.p[4])[i]);
        w2t[c * 256 + k] = f2bf(v);
        return;
    }
    i -= 65536;
    if (i < 16384) {  // W3 [256x64] -> w3t [64][256] bf16
        int k = i >> 6, c = i & 63;
        float v = ff ? ((const float*)wp.p[8])[i] : __bfloat162float(((const bf16*)wp.p[8])[i]);
        w3t[c * 256 + k] = f2bf(v);
    }
}
#define CVT_TOT (WTOT + 32768 + 65536 + 16384)

// ===== fused: CSR phase-A histogram (blocks 0..255, RAW edges) + layer-1 GEMM
//       (blocks 256..883, RAW x staged+converted inline) =====
__global__ __launch_bounds__(256) void k_fuse1(const void* __restrict__ eisrc,
                                               const void* __restrict__ xsrc,
                                               int ffh, int fih,
                                               int* __restrict__ partial,
                                               const unsigned short* __restrict__ WT16,
                                               const float* __restrict__ asf,
                                               const float* __restrict__ adf,
                                               unsigned short* __restrict__ C16,
                                               float* __restrict__ sb, float* __restrict__ db) {
    constexpr int LDW = 40;
    __shared__ alignas(16) char smem[DRANGE * 4];   // 10240 B = max(bins, As+Bs)
    __shared__ int sff, sfi;
    const int t = threadIdx.x;
    int ff = ffh, fi = fih;
    if (ffh < 0 || fih < 0) {   // same L2-broadcast sampling as k_cvt_all (all blocks agree)
        bool nanp = false, odd = false;
        const uint4* xs4 = (const uint4*)xsrc;
        uint4 a = xs4[t * 8 + 0], b = xs4[t * 8 + 4];
        const unsigned int wds[8] = {a.x, a.y, a.z, a.w, b.x, b.y, b.z, b.w};
#pragma unroll
        for (int k = 0; k < 8; k++) {
            unsigned int w2 = wds[k];
            if ((w2 & 0x7F80u) == 0x7F80u || ((w2 >> 16) & 0x7F80u) == 0x7F80u) nanp = true;
        }
        odd = ((const unsigned int*)eisrc)[2 * t + 1] != 0u;
        unsigned long long bn = __ballot(nanp);
        unsigned long long bo = __ballot(odd);
        if (t == 0) { sff = 0; sfi = 0; }
        __syncthreads();
        if ((t & 63) == 0) {
            if (bn) atomicOr(&sff, 1);
            if (bo) atomicOr(&sfi, 1);
        }
        __syncthreads();
        ff = (ffh >= 0) ? ffh : sff;
        fi = (fih >= 0) ? fih : sfi;
    }

    if (blockIdx.x < DNB * NSEG) {
        int* bins = (int*)smem;
        const int r0 = (blockIdx.x >> 6) * DRANGE;
        const int sg = blockIdx.x & 63;
        for (int i = t; i < DRANGE; i += 256) bins[i] = 0;
        __syncthreads();
        const int e1 = min(sg * ESEG + ESEG, EALL);
        for (int e = sg * ESEG + t; e < e1; e += 256) {
            int dst = (e < EE) ? iread(eisrc, fi, (long long)EE + e) : (e - EE);
            unsigned rel = dst - r0;
            if (rel < DRANGE) atomicAdd(&bins[rel], 1);
        }
        __syncthreads();
        for (int i = t; i < DRANGE; i += 256)
            partial[blockIdx.x * DRANGE + i] = bins[i];
        return;
    }
    unsigned short* As = (unsigned short*)smem;
    unsigned short* Bs = As + 64 * LDW;
    constexpr int K = 128, M = 256, H = M / 64;
    const int u = blockIdx.x - DNB * NSEG;     // 0..627
    const int bx = u % 157;
    const int hh = u / 157;
    const int row0 = bx * 64;
    const int col0 = hh * 64;
    const int wv = t >> 6;
    const int lane = t & 63;
    const int m = lane & 15;
    const int q = lane >> 4;
    const int srow = t >> 2;
    const int skoff = (t & 3) * 8;

    f32x4 acc[4] = {};
    for (int k0 = 0; k0 < K; k0 += 32) {
        {
            int grow = row0 + srow;
            uint4 av = make_uint4(0u, 0u, 0u, 0u);
            if (grow < NN) {
                if (ff) {   // fp32 x: read 32B, convert inline (same f2bf RNE as cvt did)
                    const float* xp = (const float*)xsrc + (size_t)grow * K + k0 + skoff;
                    float4 fa = *(const float4*)xp;
                    float4 fb = *(const float4*)(xp + 4);
                    union { unsigned short u16[8]; uint4 v; } pk;
                    pk.u16[0] = f2bf(fa.x); pk.u16[1] = f2bf(fa.y);
                    pk.u16[2] = f2bf(fa.z); pk.u16[3] = f2bf(fa.w);
                    pk.u16[4] = f2bf(fb.x); pk.u16[5] = f2bf(fb.y);
                    pk.u16[6] = f2bf(fb.z); pk.u16[7] = f2bf(fb.w);
                    av = pk.v;
                } else {    // bf16 storage: identity 16B copy
                    av = *(const uint4*)((const unsigned short*)xsrc + (size_t)grow * K + k0 + skoff);
                }
            }
            *(uint4*)&As[srow * LDW + skoff] = av;
            uint4 bv = *(const uint4*)&WT16[(size_t)(col0 + srow) * K + k0 + skoff];
            *(uint4*)&Bs[srow * LDW + skoff] = bv;
        }
        __syncthreads();
        bf16x8 af = *(const bf16x8*)&As[(16 * wv + m) * LDW + q * 8];
#pragma unroll
        for (int ct = 0; ct < 4; ct++) {
            bf16x8 bfv = *(const bf16x8*)&Bs[(16 * ct + m) * LDW + q * 8];
            acc[ct] = __builtin_amdgcn_mfma_f32_16x16x32_bf16(af, bfv, acc[ct], 0, 0, 0);
        }
        __syncthreads();
    }
    float asv[4], adv[4];
#pragma unroll
    for (int ct = 0; ct < 4; ct++) {
        asv[ct] = asf[hh * 64 + 16 * ct + m];
        adv[ct] = adf[hh * 64 + 16 * ct + m];
    }
#pragma unroll
    for (int reg = 0; reg < 4; reg++) {
        int row = row0 + 16 * wv + q * 4 + reg;
        float ps = 0.f, pd = 0.f;
        if (row < NN) {
#pragma unroll
            for (int ct = 0; ct < 4; ct++) {
                float v = acc[ct][reg];
                C16[(size_t)row * M + col0 + 16 * ct + m] = f2bf(v);
                ps += v * asv[ct];
                pd += v * adv[ct];
            }
        }
#pragma unroll
        for (int off = 1; off < 16; off <<= 1) {
            ps += __shfl_xor(ps, off);
            pd += __shfl_xor(pd, off);
        }
        if (m == 0 && row < NN) { sb[row * H + hh] = ps; db[row * H + hh] = pd; }
    }
}

// ================= CSR phase B1: per-bin segment reduction + local prefix ===================
__global__ void k_seg(const int* __restrict__ partial, int* __restrict__ deg,
                      int* __restrict__ segpre) {
    int bin = blockIdx.x * 256 + threadIdx.x;
    if (bin >= NN) return;
    int r = bin / DRANGE, rel = bin - r * DRANGE;
    int s = 0;
    for (int sg = 0; sg < NSEG; sg++) {
        int idx = (r * NSEG + sg) * DRANGE + rel;
        int v = partial[idx];
        segpre[idx] = s;
        s += v;
    }
    deg[bin] = s;
}

// ================= CSR phase B2: single-block scan + gstart (RAW batch) =====================
__global__ void k_scan4(const int* __restrict__ deg, int* __restrict__ rowstart,
                        const void* __restrict__ bsrc, int fih, int* __restrict__ gstart,
                        const void* __restrict__ eisrc) {
    __shared__ int part[1024];
    __shared__ int sfi;
    const int t = threadIdx.x;
    int fi = fih;
    if (fih < 0) {   // sample edge hi-words (batch dtype == edge dtype)
        bool odd = ((const unsigned int*)eisrc)[2 * t + 1] != 0u;
        unsigned long long bo = __ballot(odd);
        if (t == 0) sfi = 0;
        __syncthreads();
        if ((t & 63) == 0 && bo) atomicOr(&sfi, 1);
        __syncthreads();
        fi = sfi;
    }
    if (t <= BG) {   // gstart[t] = first n with batch[n] >= t (batch is sorted)
        int lo = 0, hi = NN;
        while (lo < hi) {
            int mid = (lo + hi) >> 1;
            int bv = iread(bsrc, fi, mid);
            if (bv < t) lo = mid + 1; else hi = mid;
        }
        gstart[t] = lo;
    }
    const int base = t * 10;
    int local[10];
    int s = 0;
    for (int i = 0; i < 10; i++) {
        int idx = base + i;
        int v = (idx < NN) ? deg[idx] : 0;
        local[i] = s; s += v;
    }
    part[t] = s; __syncthreads();
    for (int off = 1; off < 1024; off <<= 1) {
        int v = (t >= off) ? part[t - off] : 0;
        __syncthreads();
        part[t] += v;
        __syncthreads();
    }
    int pre = (t == 0) ? 0 : part[t - 1];
    for (int i = 0; i < 10; i++) {
        int idx = base + i;
        if (idx < NN) rowstart[idx] = pre + local[i];
    }
    if (t == 1023) rowstart[NN] = part[1023];
}

// ================= CSR phase C: scatter (RAW edges), LDS cursors = rowstart + segpre ========
__global__ __launch_bounds__(256) void k_scatter3(const void* __restrict__ eisrc, int fih,
                                                  const int* __restrict__ rowstart,
                                                  const int* __restrict__ segpre,
                                                  int* __restrict__ ssrc) {
    __shared__ int cur[DRANGE];
    __shared__ int sfi;
    const int t = threadIdx.x;
    int fi = fih;
    if (fih < 0) {
        bool odd = ((const unsigned int*)eisrc)[2 * t + 1] != 0u;
        unsigned long long bo = __ballot(odd);
        if (t == 0) sfi = 0;
        __syncthreads();
        if ((t & 63) == 0 && bo) atomicOr(&sfi, 1);
        __syncthreads();
        fi = sfi;
    }
    const int r0 = blockIdx.x * DRANGE;
    const int sg = blockIdx.y;
    for (int i = t; i < DRANGE; i += 256) {
        int bin = r0 + i;
        cur[i] = (bin < NN) ? rowstart[bin] + segpre[(blockIdx.x * NSEG + sg) * DRANGE + i] : 0;
    }
    __syncthreads();
    const int e1 = min(sg * ESEG + ESEG, EALL);
    for (int e = sg * ESEG + t; e < e1; e += 256) {
        int dst = (e < EE) ? iread(eisrc, fi, (long long)EE + e) : (e - EE);
        unsigned rel = dst - r0;
        if (rel < DRANGE) {
            int src = (e < EE) ? iread(eisrc, fi, e) : dst;
            int pos = atomicAdd(&cur[rel], 1);
            ssrc[pos] = src;
        }
    }
}

// ====== MFMA GEMM: h = A(bf16) @ W(bf16^T), 64x64/block, 16x16x32 mfma, fused s,d ======
template<int K, int M>
__global__ __launch_bounds__(256) void k_gemm(const unsigned short* __restrict__ A16,
                                              const unsigned short* __restrict__ WT16,
                                              const float* __restrict__ asf,
                                              const float* __restrict__ adf,
                                              unsigned short* __restrict__ C16,
                                              float* __restrict__ sb, float* __restrict__ db) {
    constexpr int BK = 32;
    constexpr int H = M / 64;
    constexpr int LDW = 40;
    __shared__ unsigned short As[64 * LDW];
    __shared__ unsigned short Bs[64 * LDW];
    const int row0 = blockIdx.x * 64;
    const int col0 = blockIdx.y * 64;
    const int hh = blockIdx.y;
    const int t = threadIdx.x;
    const int wv = t >> 6;
    const int lane = t & 63;
    const int m = lane & 15;
    const int q = lane >> 4;
    const int srow = t >> 2;
    const int skoff = (t & 3) * 8;

    f32x4 acc[4] = {};

    for (int k0 = 0; k0 < K; k0 += BK) {
        {
            int grow = row0 + srow;
            uint4 av = make_uint4(0u, 0u, 0u, 0u);
            if (grow < NN) av = *(const uint4*)&A16[(size_t)grow * K + k0 + skoff];
            *(uint4*)&As[srow * LDW + skoff] = av;
            uint4 bv = *(const uint4*)&WT16[(size_t)(col0 + srow) * K + k0 + skoff];
            *(uint4*)&Bs[srow * LDW + skoff] = bv;
        }
        __syncthreads();
        bf16x8 af = *(const bf16x8*)&As[(16 * wv + m) * LDW + q * 8];
#pragma unroll
        for (int ct = 0; ct < 4; ct++) {
            bf16x8 bfv = *(const bf16x8*)&Bs[(16 * ct + m) * LDW + q * 8];
            acc[ct] = __builtin_amdgcn_mfma_f32_16x16x32_bf16(af, bfv, acc[ct], 0, 0, 0);
        }
        __syncthreads();
    }

    float asv[4], adv[4];
#pragma unroll
    for (int ct = 0; ct < 4; ct++) {
        asv[ct] = asf[hh * 64 + 16 * ct + m];
        adv[ct] = adf[hh * 64 + 16 * ct + m];
    }
#pragma unroll
    for (int reg = 0; reg < 4; reg++) {
        int row = row0 + 16 * wv + q * 4 + reg;
        float ps = 0.f, pd = 0.f;
        if (row < NN) {
#pragma unroll
            for (int ct = 0; ct < 4; ct++) {
                float v = acc[ct][reg];
                C16[(size_t)row * M + col0 + 16 * ct + m] = f2bf(v);
                ps += v * asv[ct];
                pd += v * adv[ct];
            }
        }
#pragma unroll
        for (int off = 1; off < 16; off <<= 1) {
            ps += __shfl_xor(ps, off);
            pd += __shfl_xor(pd, off);
        }
        if (m == 0 && row < NN) { sb[row * H + hh] = ps; db[row * H + hh] = pd; }
    }
}

// ===== R27: barrier-free-main-loop agg. Each gather thread computes its own weight
// inline (8x redundant exp per head — VALU-cheap); ssrc/sb read directly (broadcast
// loads); wl/srcl LDS and the per-chunk double barrier are GONE. wsum reduces via
// shfl_xor across the eg dimension (+1 tiny LDS step for H=4). acc summation order
// is BIT-IDENTICAL to R25 (same j≡eg mod 8 increasing order); only wsum rounding
// shifts (threshold headroom 4.7x). 2 barriers per NODE total.
template<int H>
__global__ void k_agg(const unsigned short* __restrict__ hbuf16, const float* __restrict__ sb,
                      const float* __restrict__ db, const int* __restrict__ rowstart,
                      const int* __restrict__ ssrc, const float* __restrict__ bias,
                      unsigned short* __restrict__ out16) {
    constexpr int M = H * 64;                  // 256 (H=4) or 64 (H=1); also blockDim.x
    constexpr int NW = M / 64;                 // waves per block
    constexpr int CG = M / 8;                  // 8-channel groups: 32 or 8
    constexpr int LCG = (H == 4) ? 5 : 3;
    const int n = blockIdx.x;
    const int tid = threadIdx.x;
    const int start = rowstart[n], end = rowstart[n + 1];
    const int wv = tid >> 6;
    const int lane = tid & 63;
    const int cg = tid & (CG - 1);             // channel group
    const int eg = tid >> LCG;                 // edge subgroup 0..7
    const int chh = (H == 4) ? (cg >> 3) : 0;  // head of this thread's channel block
    __shared__ float accbuf[8 * M];            // [eg][channel]
    __shared__ float sww[NW][H];               // per-wave per-head wsum (H=4 only)
    const float dn = db[n * H + chh];

    // ---- single barrier-free sweep: inline weight + gather, unroll-4 for MLP ----
    float wsum = 0.f;
    float acc[8] = {};
#pragma unroll 4
    for (int p = start + eg; p < end; p += 8) {
        int s = ssrc[p];                               // 32-lane broadcast load
        float e = sb[s * H + chh] + dn;
        e = e > 0.f ? e : 0.2f * e;
        float w2 = __expf(e);
        wsum += w2;
        const bf16x8 v = *(const bf16x8*)&hbuf16[(size_t)s * M + cg * 8];
#pragma unroll
        for (int i = 0; i < 8; i++)
            acc[i] += w2 * bf2f((unsigned short)v[i]);
    }

    // ---- dump per-thread acc to LDS; reduce wsum across eg ----
    {
        float* ab = &accbuf[eg * M + cg * 8];
#pragma unroll
        for (int i = 0; i < 8; i++) ab[i] = acc[i];
    }
    if constexpr (NW > 1) {
        // wave w holds egs {2w, 2w+1} at lane<32 / lane>=32 (same cg) -> pair via xor 32
        wsum += __shfl_xor(wsum, 32);
        if (lane < 32 && (cg & 7) == 0) sww[wv][chh] = wsum;   // lanes 0,8,16,24
    } else {
        // H==1: eg spans lane bits 3,4,5 -> full butterfly, no LDS
        wsum += __shfl_xor(wsum, 8);
        wsum += __shfl_xor(wsum, 16);
        wsum += __shfl_xor(wsum, 32);
    }
    __syncthreads();

    float wsh;
    if constexpr (NW > 1) {
        const int h2 = tid >> 6;
        wsh = sww[0][h2] + sww[1][h2] + sww[2][h2] + sww[3][h2];
    } else {
        wsh = wsum;
    }

    // ---- cross-edge-group reduce (conflict-free: accbuf[e8*M + tid] is consecutive) ----
    float o = 0.f;
#pragma unroll
    for (int e8 = 0; e8 < 8; e8++) o += accbuf[e8 * M + tid];
    o = o / wsh + bias[tid];
    out16[(size_t)n * M + tid] = f2bf(fmaxf(o, 0.f));
}

// ====== fused: global mean pool (bf16 feat) -> hidden -> actor/critic out ==================
__global__ __launch_bounds__(256) void k_final(const unsigned short* __restrict__ feat16,
                                               const int* __restrict__ gstart,
                                               const float* __restrict__ Wa1, const float* __restrict__ ba1,
                                               const float* __restrict__ Wc1, const float* __restrict__ bc1,
                                               const float* __restrict__ Wa2, const float* __restrict__ ba2,
                                               const float* __restrict__ Wc2, const float* __restrict__ bc2,
                                               float* __restrict__ out) {
    __shared__ float red[256];
    __shared__ float p[64];
    __shared__ float a[64], cc[64];
    const int g = blockIdx.x, t = threadIdx.x;
    const int d = t & 63, c = t >> 6;
    const int s = gstart[g], e = gstart[g + 1];
    float acc = 0.f;
    for (int n = s + c; n < e; n += 4) acc += bf2f(feat16[(size_t)n * 64 + d]);
    red[t] = acc; __syncthreads();
    if (c == 0) p[d] = (red[d] + red[64 + d] + red[128 + d] + red[192 + d])
                       / fmaxf((float)(e - s), 1.f);
    __syncthreads();
    if (t < 128) {
        int j = t & 63;
        const float* W  = (t < 64) ? Wa1 : Wc1;
        const float* bb = (t < 64) ? ba1 : bc1;
        float h = 0.f;
#pragma unroll 8
        for (int k = 0; k < 64; k++) h += p[k] * W[k * 64 + j];
        h = fmaxf(h + bb[j], 0.f);
        if (t < 64) a[j] = h; else cc[j] = h;
    }
    __syncthreads();
    float o[4] = {0.f, 0.f, 0.f, 0.f};
    for (int k = 0; k < 64; k++) {
        float ak = a[k];
#pragma unroll
        for (int q = 0; q < 4; q++) o[q] += ak * Wa2[k * AOUT + t + 256 * q];
    }
#pragma unroll
    for (int q = 0; q < 4; q++)
        out[g * AOUT + t + 256 * q] = tanhf(o[q] + ba2[t + 256 * q]);
    if (t == 0) {
        float v = 0.f;
        for (int k = 0; k < 64; k++) v += cc[k] * Wc2[k];
        out[BG * AOUT + g] = v + bc2[0];
    }
}

extern "C" void kernel_launch(void* const* d_in, const int* in_sizes, int n_in,
                              void* d_out, int out_size, void* d_ws, size_t ws_size,
                              hipStream_t stream) {
    float* out = (float*)d_out;

    char* w = (char*)d_ws;
    auto alloc = [&](size_t bytes) { void* p = (void*)w; w += (bytes + 255) & ~size_t(255); return p; };
    float* wf      = (float*)alloc((size_t)WTOT * 4);
    unsigned short* w1t    = (unsigned short*)alloc((size_t)32768 * 2);
    unsigned short* w2t    = (unsigned short*)alloc((size_t)65536 * 2);
    unsigned short* w3t    = (unsigned short*)alloc((size_t)16384 * 2);
    unsigned short* actA16 = (unsigned short*)alloc((size_t)NN * 256 * 2);
    unsigned short* actB16 = (unsigned short*)alloc((size_t)NN * 256 * 2);
    float* sb      = (float*)alloc((size_t)NN * 4 * 4);
    float* db      = (float*)alloc((size_t)NN * 4 * 4);
    int*   partial = (int*)alloc((size_t)DNB * NSEG * DRANGE * 4);
    int*   segpre  = (int*)alloc((size_t)DNB * NSEG * DRANGE * 4);
    int*   deg     = (int*)alloc((size_t)NN * 4);
    int*   rowstart= (int*)alloc((size_t)(NN + 1) * 4);
    int*   ssrc    = (int*)alloc((size_t)EALL * 4);
    int*   gstart  = (int*)alloc((size_t)(BG + 1) * 4);

    // ---- host-side dtype decision from in_sizes (bytes); device samples otherwise ----
    int ffh = -1, fih = -1;
    if (in_sizes && n_in >= 2) {
        long long xs = in_sizes[0];
        if (xs == (long long)NN * 128 * 4) ffh = 1;
        else if (xs == (long long)NN * 128 * 2) ffh = 0;
        long long es = in_sizes[1];
        if (es == (long long)2 * EE * 8) fih = 0;
        else if (es == (long long)2 * EE * 4) fih = 1;
    }

    // ---- weight conversion only (edges/batch/x consumed raw downstream) ----
    WPtrs wp;
    for (int s = 0; s < 20; s++) wp.p[s] = d_in[3 + s];
    k_cvt_all<<<(CVT_TOT + 255) / 256, 256, 0, stream>>>(
        wp, d_in[0], wf, w1t, w2t, w3t, ffh);

    const int wsz[20] = {32768,256,256,256,65536,256,256,256,16384,64,64,64,4096,64,65536,1024,4096,64,64,1};
    int woff[20]; int acc = 0;
    for (int s = 0; s < 20; s++) { woff[s] = acc; acc += wsz[s]; }
    const float *as1f = wf + woff[1], *ad1f = wf + woff[2], *b1f = wf + woff[3];
    const float *as2f = wf + woff[5], *ad2f = wf + woff[6], *b2f = wf + woff[7];
    const float *as3f = wf + woff[9], *ad3f = wf + woff[10], *b3f = wf + woff[11];
    const float *Wa1f = wf + woff[12], *ba1f = wf + woff[13], *Wa2f = wf + woff[14], *ba2f = wf + woff[15];
    const float *Wc1f = wf + woff[16], *bc1f = wf + woff[17], *Wc2f = wf + woff[18], *bc2f = wf + woff[19];

    // ---- fused: CSR histogram (256 blocks, raw edges) + Layer-1 GEMM (628 blocks, raw x) ----
    k_fuse1<<<DNB * NSEG + 628, 256, 0, stream>>>(d_in[1], d_in[0], ffh, fih, partial,
                                                  w1t, as1f, ad1f, actA16, sb, db);

    // ---- CSR finish ----
    k_seg<<<(NN + 255) / 256, 256, 0, stream>>>(partial, deg, segpre);
    k_scan4<<<1, 1024, 0, stream>>>(deg, rowstart, d_in[2], fih, gstart, d_in[1]);
    k_scatter3<<<dim3(DNB, NSEG), 256, 0, stream>>>(d_in[1], fih, rowstart, segpre, ssrc);

    // ---- Layer 1 aggregate ----
    k_agg<4><<<NN, 256, 0, stream>>>(actA16, sb, db, rowstart, ssrc, b1f, actB16);

    // ---- Layer 2 ----
    k_gemm<256, 256><<<dim3(157, 4), 256, 0, stream>>>(actB16, w2t, as2f, ad2f, actA16, sb, db);
    k_agg<4><<<NN, 256, 0, stream>>>(actA16, sb, db, rowstart, ssrc, b2f, actB16);

    // ---- Layer 3 ----
    k_gemm<256, 64><<<dim3(157, 1), 256, 0, stream>>>(actB16, w3t, as3f, ad3f, actA16, sb, db);
    k_agg<1><<<NN, 64, 0, stream>>>(actA16, sb, db, rowstart, ssrc, b3f, actB16);

    // ---- fused pool + heads ----
    k_final<<<BG, 256, 0, stream>>>(actB16, gstart,
                                    Wa1f, ba1f, Wc1f, bc1f, Wa2f, ba2f, Wc2f, bc2f, out);
}